// Round 12
// baseline (25.891 us; speedup 1.0000x reference)
//
#include <hip/hip_runtime.h>

// Problem constants (from reference setup_inputs)
#define N_NODES 50000
#define N_EDGES 600000
#define D_FEAT 128

// Native clang vector types (16B/8B vector ops)
typedef float vfloat4 __attribute__((ext_vector_type(4)));
typedef float vfloat2 __attribute__((ext_vector_type(2)));
typedef int   vint2   __attribute__((ext_vector_type(2)));

#define LOG2E 1.4426950408889634f

// ---------------------------------------------------------------------------
// DIAGNOSTIC ROUND 3: r6 code exactly, but k1 launched TWICE (idempotent).
//   dur - 20.195 (r6 anchor) = t_k1 + g;  g = 1.5us (r9);  K = 12.1us (r8)
// -> pins the k1/k2 split of K, directing the final optimization (or the
//    roofline declaration). Output identical to r6.
// ---------------------------------------------------------------------------

// Kernel 1 (r6 exact): 32 lanes/node, 16B/lane h loads, 5-shuffle parity
// reduce, lanes 0-3 write 4B each (16B coalesced per node).
__global__ __launch_bounds__(256) void node_proj_kernel(
    const vfloat4* __restrict__ h4, // [N_NODES * 32] (= [N_NODES, 128] f32)
    const float* __restrict__ W,    // [256, 2] row-major
    float* __restrict__ pqf)        // [N_NODES * 4]
{
    const int tid = blockIdx.x * blockDim.x + threadIdx.x;
    const int node = tid >> 5;              // 32 lanes per node
    if (node >= N_NODES) return;
    const int gl = threadIdx.x & 31;        // lane within 32-group

    const vfloat4 hv = h4[(size_t)node * 32 + gl];

    const vfloat4 wt0 = *reinterpret_cast<const vfloat4*>(W + 8 * gl);
    const vfloat4 wt1 = *reinterpret_cast<const vfloat4*>(W + 8 * gl + 4);
    const vfloat4 wb0 = *reinterpret_cast<const vfloat4*>(W + 256 + 8 * gl);
    const vfloat4 wb1 = *reinterpret_cast<const vfloat4*>(W + 256 + 8 * gl + 4);

    const float p0 = hv.x * wt0.x + hv.y * wt0.z + hv.z * wt1.x + hv.w * wt1.z;
    const float p1 = hv.x * wt0.y + hv.y * wt0.w + hv.z * wt1.y + hv.w * wt1.w;
    const float q0 = hv.x * wb0.x + hv.y * wb0.z + hv.z * wb1.x + hv.w * wb1.z;
    const float q1 = hv.x * wb0.y + hv.y * wb0.w + hv.z * wb1.y + hv.w * wb1.w;

    const bool o1 = gl & 1;
    float v = o1 ? p1 : p0;
    float u = o1 ? p0 : p1;
    v += __shfl_xor(u, 1, 64);
    float x = o1 ? q1 : q0;
    float y = o1 ? q0 : q1;
    x += __shfl_xor(y, 1, 64);

    const bool o2 = gl & 2;
    float z = o2 ? x : v;
    float t = o2 ? v : x;
    z += __shfl_xor(t, 2, 64);

    z += __shfl_xor(z, 4, 64);
    z += __shfl_xor(z, 8, 64);
    z += __shfl_xor(z, 16, 64);

    if (gl < 4) pqf[(size_t)node * 4 + gl] = z;
}

// Kernel 2 (r6 exact): 2 edges/thread; float2 gathers from the pq table;
// softmax(sigmoid(l), axis=1) over 2 classes == sigmoid(s0-s1).
__device__ __forceinline__ float fast_sigmoid(float x) {
    return __builtin_amdgcn_rcpf(1.0f + __builtin_amdgcn_exp2f(-x * LOG2E));
}

__device__ __forceinline__ vfloat2 edge_out(float we, int s, int d,
                                            const float* __restrict__ pq,
                                            float b0, float b1)
{
    const vfloat2 ps = *reinterpret_cast<const vfloat2*>(pq + (size_t)s * 4);
    const vfloat2 qd = *reinterpret_cast<const vfloat2*>(pq + (size_t)d * 4 + 2);
    const float l0 = we * (ps.x + qd.x) + b0;
    const float l1 = we * (ps.y + qd.y) + b1;
    const float s0 = fast_sigmoid(l0);
    const float s1 = fast_sigmoid(l1);
    const float o0 = fast_sigmoid(s0 - s1);
    vfloat2 r; r.x = o0; r.y = 1.0f - o0;
    return r;
}

__global__ __launch_bounds__(256) void edge_kernel(
    const float* __restrict__ w,     // [N_EDGES]
    const int* __restrict__ src,     // [N_EDGES]
    const int* __restrict__ dst,     // [N_EDGES]
    const float* __restrict__ pq,    // [N_NODES * 4]
    const float* __restrict__ b,     // [2]
    vfloat4* __restrict__ out4)      // [N_EDGES/2] (= [N_EDGES, 2] f32)
{
    const int t = blockIdx.x * blockDim.x + threadIdx.x;
    if (t >= N_EDGES / 2) return;

    const vfloat2 wv = *reinterpret_cast<const vfloat2*>(w + 2 * t);
    const vint2 sv = *reinterpret_cast<const vint2*>(src + 2 * t);
    const vint2 dv = *reinterpret_cast<const vint2*>(dst + 2 * t);
    const float b0 = b[0], b1 = b[1];

    const vfloat2 r0 = edge_out(wv.x, sv.x, dv.x, pq, b0, b1);
    const vfloat2 r1 = edge_out(wv.y, sv.y, dv.y, pq, b0, b1);

    vfloat4 o; o.x = r0.x; o.y = r0.y; o.z = r1.x; o.w = r1.y;
    out4[t] = o;
}

extern "C" void kernel_launch(void* const* d_in, const int* in_sizes, int n_in,
                              void* d_out, int out_size, void* d_ws, size_t ws_size,
                              hipStream_t stream) {
    const float* h   = (const float*)d_in[0];  // [50000,128]
    const float* w   = (const float*)d_in[1];  // [600000,1]
    const int*   src = (const int*)d_in[2];    // [600000]
    const int*   dst = (const int*)d_in[3];    // [600000]
    const float* W   = (const float*)d_in[4];  // [256,2]
    const float* b   = (const float*)d_in[5];  // [2]

    float* pq = (float*)d_ws;                  // 50000 * 16 B = 800 KB scratch
    vfloat4* out = (vfloat4*)d_out;
    const vfloat4* h4 = reinterpret_cast<const vfloat4*>(h);

    const int n_blocks1 = (N_NODES * 32 + 255) / 256;  // 6250
    const int n_blocks2 = (N_EDGES / 2 + 255) / 256;   // 1172

    // k1 launched twice (idempotent): dur - r6_anchor = t_k1 + g
    node_proj_kernel<<<n_blocks1, 256, 0, stream>>>(h4, W, pq);
    node_proj_kernel<<<n_blocks1, 256, 0, stream>>>(h4, W, pq);
    edge_kernel<<<n_blocks2, 256, 0, stream>>>(w, src, dst, pq, b, out);
}

// Round 13
// 20.449 us; speedup vs baseline: 1.2661x; 1.2661x over previous
//
#include <hip/hip_runtime.h>

// Problem constants (from reference setup_inputs)
#define N_NODES 50000
#define N_EDGES 600000
#define D_FEAT 128

// Native clang vector types (16B/8B vector ops)
typedef float vfloat4 __attribute__((ext_vector_type(4)));
typedef float vfloat2 __attribute__((ext_vector_type(2)));

#define LOG2E 1.4426950408889634f

// ---------------------------------------------------------------------------
// Kernel 1 (r6 exact — measured at its 4.2us memory floor): 32 lanes/node,
// 16B/lane h loads, 5-shuffle parity reduce, lanes 0-3 write 4B each
// (16B coalesced per node).
// ---------------------------------------------------------------------------
__global__ __launch_bounds__(256) void node_proj_kernel(
    const vfloat4* __restrict__ h4, // [N_NODES * 32] (= [N_NODES, 128] f32)
    const float* __restrict__ W,    // [256, 2] row-major
    float* __restrict__ pqf)        // [N_NODES * 4]
{
    const int tid = blockIdx.x * blockDim.x + threadIdx.x;
    const int node = tid >> 5;              // 32 lanes per node
    if (node >= N_NODES) return;
    const int gl = threadIdx.x & 31;        // lane within 32-group

    const vfloat4 hv = h4[(size_t)node * 32 + gl];

    const vfloat4 wt0 = *reinterpret_cast<const vfloat4*>(W + 8 * gl);
    const vfloat4 wt1 = *reinterpret_cast<const vfloat4*>(W + 8 * gl + 4);
    const vfloat4 wb0 = *reinterpret_cast<const vfloat4*>(W + 256 + 8 * gl);
    const vfloat4 wb1 = *reinterpret_cast<const vfloat4*>(W + 256 + 8 * gl + 4);

    const float p0 = hv.x * wt0.x + hv.y * wt0.z + hv.z * wt1.x + hv.w * wt1.z;
    const float p1 = hv.x * wt0.y + hv.y * wt0.w + hv.z * wt1.y + hv.w * wt1.w;
    const float q0 = hv.x * wb0.x + hv.y * wb0.z + hv.z * wb1.x + hv.w * wb1.z;
    const float q1 = hv.x * wb0.y + hv.y * wb0.w + hv.z * wb1.y + hv.w * wb1.w;

    const bool o1 = gl & 1;
    float v = o1 ? p1 : p0;
    float u = o1 ? p0 : p1;
    v += __shfl_xor(u, 1, 64);
    float x = o1 ? q1 : q0;
    float y = o1 ? q0 : q1;
    x += __shfl_xor(y, 1, 64);

    const bool o2 = gl & 2;
    float z = o2 ? x : v;
    float t = o2 ? v : x;
    z += __shfl_xor(t, 2, 64);

    z += __shfl_xor(z, 4, 64);
    z += __shfl_xor(z, 8, 64);
    z += __shfl_xor(z, 16, 64);

    if (gl < 4) pqf[(size_t)node * 4 + gl] = z;
}

// ---------------------------------------------------------------------------
// Kernel 2: 1 edge per thread (2344 blocks = 2x the waves of the r6 version)
// — final TLP experiment for the gather phase. Streams are 4B/lane but fully
// coalesced per wave; gathers are 8B from the L2-resident pq table; 8B
// coalesced stores. softmax(sigmoid(l), axis=1) over 2 == sigmoid(s0-s1).
// ---------------------------------------------------------------------------
__device__ __forceinline__ float fast_sigmoid(float x) {
    return __builtin_amdgcn_rcpf(1.0f + __builtin_amdgcn_exp2f(-x * LOG2E));
}

__global__ __launch_bounds__(256) void edge_kernel(
    const float* __restrict__ w,     // [N_EDGES]
    const int* __restrict__ src,     // [N_EDGES]
    const int* __restrict__ dst,     // [N_EDGES]
    const float* __restrict__ pq,    // [N_NODES * 4]
    const float* __restrict__ b,     // [2]
    vfloat2* __restrict__ out2)      // [N_EDGES] (= [N_EDGES, 2] f32)
{
    const int e = blockIdx.x * blockDim.x + threadIdx.x;
    if (e >= N_EDGES) return;

    const float we = w[e];
    const int s = src[e];
    const int d = dst[e];

    const vfloat2 ps = *reinterpret_cast<const vfloat2*>(pq + (size_t)s * 4);
    const vfloat2 qd = *reinterpret_cast<const vfloat2*>(pq + (size_t)d * 4 + 2);
    const float b0 = b[0], b1 = b[1];

    const float l0 = we * (ps.x + qd.x) + b0;
    const float l1 = we * (ps.y + qd.y) + b1;
    const float s0 = fast_sigmoid(l0);
    const float s1 = fast_sigmoid(l1);
    const float o0 = fast_sigmoid(s0 - s1);

    vfloat2 o; o.x = o0; o.y = 1.0f - o0;
    out2[e] = o;
}

extern "C" void kernel_launch(void* const* d_in, const int* in_sizes, int n_in,
                              void* d_out, int out_size, void* d_ws, size_t ws_size,
                              hipStream_t stream) {
    const float* h   = (const float*)d_in[0];  // [50000,128]
    const float* w   = (const float*)d_in[1];  // [600000,1]
    const int*   src = (const int*)d_in[2];    // [600000]
    const int*   dst = (const int*)d_in[3];    // [600000]
    const float* W   = (const float*)d_in[4];  // [256,2]
    const float* b   = (const float*)d_in[5];  // [2]

    float* pq = (float*)d_ws;                  // 50000 * 16 B = 800 KB scratch
    vfloat2* out = (vfloat2*)d_out;

    // Kernel 1: 32 lanes/node -> 1.6M threads, 6250 blocks of 256
    const int n_blocks1 = (N_NODES * 32 + 255) / 256;
    node_proj_kernel<<<n_blocks1, 256, 0, stream>>>(
        reinterpret_cast<const vfloat4*>(h), W, pq);

    // Kernel 2: 1 edge/thread -> 600000 threads, 2344 blocks of 256
    const int n_blocks2 = (N_EDGES + 255) / 256;
    edge_kernel<<<n_blocks2, 256, 0, stream>>>(w, src, dst, pq, b, out);
}

// Round 14
// 20.136 us; speedup vs baseline: 1.2858x; 1.0156x over previous
//
#include <hip/hip_runtime.h>

// Problem constants (from reference setup_inputs)
#define N_NODES 50000
#define N_EDGES 600000
#define D_FEAT 128

// Native clang vector types (16B/8B vector ops)
typedef float vfloat4 __attribute__((ext_vector_type(4)));
typedef float vfloat2 __attribute__((ext_vector_type(2)));
typedef int   vint2   __attribute__((ext_vector_type(2)));

#define LOG2E 1.4426950408889634f

// ---------------------------------------------------------------------------
// FINAL (r6-exact, best measured: 20.195us). Budget, all terms measured:
//   F~5.2us graph base + 2 gaps ~3us + k1 4.2us (25.6MB @ 6.1TB/s = floor)
//   + k2 ~7.9us (2.4M random gather line-requests, TA-issue-bound; MLP/TLP/
//   geometry/NT all null r7/r13). Fusion refuted (cross-XCD barrier 54-80us,
//   r5/r10). Algebraic factorization: per-edge matmul distributes over the
//   scalar edge weight -> precompute p=h.W_top, q=h.W_bot per node (800KB),
//   cutting 600MB of per-edge h-gathers to 38MB total traffic.
// ---------------------------------------------------------------------------

// Kernel 1: per-node projection. 32 lanes/node, 16B/lane coalesced h loads,
// 5-shuffle parity reduce, lanes 0-3 write 4B each (16B coalesced per node).
__global__ __launch_bounds__(256) void node_proj_kernel(
    const vfloat4* __restrict__ h4, // [N_NODES * 32] (= [N_NODES, 128] f32)
    const float* __restrict__ W,    // [256, 2] row-major
    float* __restrict__ pqf)        // [N_NODES * 4]
{
    const int tid = blockIdx.x * blockDim.x + threadIdx.x;
    const int node = tid >> 5;              // 32 lanes per node
    if (node >= N_NODES) return;
    const int gl = threadIdx.x & 31;        // lane within 32-group

    const vfloat4 hv = h4[(size_t)node * 32 + gl];

    // W rows for cols k=4*gl..4*gl+3: 2 KB total -> L1-resident.
    const vfloat4 wt0 = *reinterpret_cast<const vfloat4*>(W + 8 * gl);
    const vfloat4 wt1 = *reinterpret_cast<const vfloat4*>(W + 8 * gl + 4);
    const vfloat4 wb0 = *reinterpret_cast<const vfloat4*>(W + 256 + 8 * gl);
    const vfloat4 wb1 = *reinterpret_cast<const vfloat4*>(W + 256 + 8 * gl + 4);

    const float p0 = hv.x * wt0.x + hv.y * wt0.z + hv.z * wt1.x + hv.w * wt1.z;
    const float p1 = hv.x * wt0.y + hv.y * wt0.w + hv.z * wt1.y + hv.w * wt1.w;
    const float q0 = hv.x * wb0.x + hv.y * wb0.z + hv.z * wb1.x + hv.w * wb1.z;
    const float q1 = hv.x * wb0.y + hv.y * wb0.w + hv.z * wb1.y + hv.w * wb1.w;

    // Step 1 (xor 1): even lanes accumulate p0/q0, odd lanes p1/q1.
    const bool o1 = gl & 1;
    float v = o1 ? p1 : p0;
    float u = o1 ? p0 : p1;
    v += __shfl_xor(u, 1, 64);
    float x = o1 ? q1 : q0;
    float y = o1 ? q0 : q1;
    x += __shfl_xor(y, 1, 64);

    // Step 2 (xor 2): bit1=0 lanes keep P, bit1=1 lanes keep Q.
    const bool o2 = gl & 2;
    float z = o2 ? x : v;
    float t = o2 ? v : x;
    z += __shfl_xor(t, 2, 64);

    // Steps 3-5: lane gl holds component (gl&3); sum across the 32-group.
    z += __shfl_xor(z, 4, 64);
    z += __shfl_xor(z, 8, 64);
    z += __shfl_xor(z, 16, 64);

    if (gl < 4) pqf[(size_t)node * 4 + gl] = z;
}

// Kernel 2: 2 edges/thread; 8B coalesced stream loads, 8B gathers from the
// L2-resident pq table, 16B coalesced stores.
// softmax(sigmoid(l), axis=1) over 2 classes == sigmoid(s0-s1).
__device__ __forceinline__ float fast_sigmoid(float x) {
    return __builtin_amdgcn_rcpf(1.0f + __builtin_amdgcn_exp2f(-x * LOG2E));
}

__device__ __forceinline__ vfloat2 edge_out(float we, int s, int d,
                                            const float* __restrict__ pq,
                                            float b0, float b1)
{
    // ps needs pq[s*4+0..1] (p of src); qd needs pq[d*4+2..3] (q of dst)
    const vfloat2 ps = *reinterpret_cast<const vfloat2*>(pq + (size_t)s * 4);
    const vfloat2 qd = *reinterpret_cast<const vfloat2*>(pq + (size_t)d * 4 + 2);
    const float l0 = we * (ps.x + qd.x) + b0;
    const float l1 = we * (ps.y + qd.y) + b1;
    const float s0 = fast_sigmoid(l0);
    const float s1 = fast_sigmoid(l1);
    const float o0 = fast_sigmoid(s0 - s1);
    vfloat2 r; r.x = o0; r.y = 1.0f - o0;
    return r;
}

__global__ __launch_bounds__(256) void edge_kernel(
    const float* __restrict__ w,     // [N_EDGES]
    const int* __restrict__ src,     // [N_EDGES]
    const int* __restrict__ dst,     // [N_EDGES]
    const float* __restrict__ pq,    // [N_NODES * 4]
    const float* __restrict__ b,     // [2]
    vfloat4* __restrict__ out4)      // [N_EDGES/2] (= [N_EDGES, 2] f32)
{
    const int t = blockIdx.x * blockDim.x + threadIdx.x;
    if (t >= N_EDGES / 2) return;

    const vfloat2 wv = *reinterpret_cast<const vfloat2*>(w + 2 * t);
    const vint2 sv = *reinterpret_cast<const vint2*>(src + 2 * t);
    const vint2 dv = *reinterpret_cast<const vint2*>(dst + 2 * t);
    const float b0 = b[0], b1 = b[1];

    const vfloat2 r0 = edge_out(wv.x, sv.x, dv.x, pq, b0, b1);
    const vfloat2 r1 = edge_out(wv.y, sv.y, dv.y, pq, b0, b1);

    vfloat4 o; o.x = r0.x; o.y = r0.y; o.z = r1.x; o.w = r1.y;
    out4[t] = o;
}

extern "C" void kernel_launch(void* const* d_in, const int* in_sizes, int n_in,
                              void* d_out, int out_size, void* d_ws, size_t ws_size,
                              hipStream_t stream) {
    const float* h   = (const float*)d_in[0];  // [50000,128]
    const float* w   = (const float*)d_in[1];  // [600000,1]
    const int*   src = (const int*)d_in[2];    // [600000]
    const int*   dst = (const int*)d_in[3];    // [600000]
    const float* W   = (const float*)d_in[4];  // [256,2]
    const float* b   = (const float*)d_in[5];  // [2]

    float* pq = (float*)d_ws;                  // 50000 * 16 B = 800 KB scratch
    vfloat4* out = (vfloat4*)d_out;

    // Kernel 1: 32 lanes/node -> 1.6M threads, 6250 blocks of 256
    const int n_blocks1 = (N_NODES * 32 + 255) / 256;
    node_proj_kernel<<<n_blocks1, 256, 0, stream>>>(
        reinterpret_cast<const vfloat4*>(h), W, pq);

    // Kernel 2: 2 edges/thread -> 300000 threads, 1172 blocks of 256
    const int n_blocks2 = (N_EDGES / 2 + 255) / 256;
    edge_kernel<<<n_blocks2, 256, 0, stream>>>(w, src, dst, pq, b, out);
}